// Round 14
// baseline (268.112 us; speedup 1.0000x reference)
//
#include <hip/hip_runtime.h>

#define NN 4096
#define DD 512
#define FF 512
#define HH 4
#define KK 1024   // concat GEMM depth

typedef _Float16 f16;
typedef f16 f16x8 __attribute__((ext_vector_type(8)));
typedef f16 f16x4 __attribute__((ext_vector_type(4)));
typedef float f32x4 __attribute__((ext_vector_type(4)));

// ---------------- async global->LDS (16 B per lane; LDS dest = uniform base + lane*16) ----------------
typedef __attribute__((address_space(1))) void gvoid;
typedef __attribute__((address_space(3))) void svoid;
__device__ __forceinline__ void glds16(const void* g, void* s) {
    __builtin_amdgcn_global_load_lds((gvoid*)g, (svoid*)s, 16, 0, 0);
}

// ---------------- static device workspace (fully rewritten every call) ----------------
__device__ __attribute__((aligned(16))) f16 g_catA[NN * KK];         //  8 MB  [n][ nodes(512) | X(512) ]
__device__ __attribute__((aligned(16))) f16 g_catB[HH * FF * KK];    //  4 MB  [h][f][ W_h^T(512) | We^T(512) ]
__device__ __attribute__((aligned(16))) f16 g_featsH[HH * FF * NN];  // 16 MB  (feats+e)^T
__device__ __attribute__((aligned(16))) f16 g_oaccH[(size_t)2 * HH * NN * FF]; // 33.5 MB f16 partial slabs
__device__ float g_bcat[HH * FF];                                    // b_h[f] + be[f]
__device__ float g_tu[HH * DD], g_tv[HH * DD], g_bu[HH], g_bv[HH];
__device__ float g_p[HH * NN], g_q[HH * NN], g_M[HH * NN], g_sc[HH * NN];

#define PREP_CONV 4104    // (2*NN*DD/4 + HH*FF) / 256 blocks
#define PREP_TRAN 320
#define PREP_UV   513

// ---------------- fused prep: fp32->f16 concat staging (vectorized) + transposes + u/v proj ----------------
__global__ __launch_bounds__(256) void k_prep(const float* __restrict__ nodes, const float* __restrict__ edges,
                                              const float* __restrict__ labels, const float* __restrict__ We,
                                              const float* __restrict__ W, const float* __restrict__ be,
                                              const float* __restrict__ b, const float* __restrict__ u,
                                              const float* __restrict__ v) {
    __shared__ float lds[64 * 65];
    int bx = blockIdx.x;
    int tid = threadIdx.x;
    if (bx < PREP_CONV) {
        int id = bx * 256 + tid;
        const int NQ = NN * DD / 4;              // 524288 float4 groups
        if (id < NQ) {                           // nodes -> catA[:, 0:512]
            f32x4 vv = *(const f32x4*)(nodes + (size_t)id * 4);
            f16x4 ov;
#pragma unroll
            for (int k = 0; k < 4; ++k) ov[k] = (f16)vv[k];
            *(f16x4*)&g_catA[(size_t)(id >> 7) * KK + (id & 127) * 4] = ov;
            return;
        }
        id -= NQ;
        if (id < NQ) {                           // edges+labels -> catA[:, 512:1024]
            f32x4 ev = *(const f32x4*)(edges  + (size_t)id * 4);
            f32x4 lv = *(const f32x4*)(labels + (size_t)id * 4);
            f16x4 ov;
#pragma unroll
            for (int k = 0; k < 4; ++k) ov[k] = (f16)(ev[k] + lv[k]);
            *(f16x4*)&g_catA[(size_t)(id >> 7) * KK + 512 + (id & 127) * 4] = ov;
            return;
        }
        id -= NQ;
        if (id < HH * FF) { g_bcat[id] = b[id] + be[id & 511]; return; }
        return;
    }
    if (bx < PREP_CONV + PREP_TRAN) {
        int bid = bx - PREP_CONV;                    // 0..319
        int mi = bid >> 6;                           // 0 = We, 1..4 = W head
        int t64 = bid & 63;
        const float* src = (mi == 0) ? We : (W + (size_t)(mi - 1) * DD * FF);
        int ti = t64 >> 3, tj = t64 & 7;             // 64x64 tile coords in [d][f]
        int r = tid >> 2, cseg = (tid & 3) * 16;
#pragma unroll
        for (int kq = 0; kq < 4; ++kq) {
            f32x4 vv = *(const f32x4*)(src + (size_t)(ti * 64 + r) * 512 + tj * 64 + cseg + kq * 4);
            *(f32x4*)&lds[r * 65 + cseg + kq * 4] = vv;
        }
        __syncthreads();
        int fl = tid >> 2, dseg = (tid & 3) * 16;
        f16x8 o0, o1;
#pragma unroll
        for (int k = 0; k < 8; ++k) o0[k] = (f16)lds[(dseg + k) * 65 + fl];
#pragma unroll
        for (int k = 0; k < 8; ++k) o1[k] = (f16)lds[(dseg + 8 + k) * 65 + fl];
        size_t frow = (size_t)(tj * 64 + fl);
        size_t dcol = (size_t)(ti * 64 + dseg);
        if (mi == 0) {                               // We^T -> every head's [512:1024] slice
#pragma unroll
            for (int hh = 0; hh < HH; ++hh) {
                size_t ob = ((size_t)hh * FF + frow) * KK + 512 + dcol;
                *(f16x8*)&g_catB[ob] = o0;
                *(f16x8*)&g_catB[ob + 8] = o1;
            }
        } else {                                     // W_h^T -> head's [0:512] slice
            size_t ob = ((size_t)(mi - 1) * FF + frow) * KK + dcol;
            *(f16x8*)&g_catB[ob] = o0;
            *(f16x8*)&g_catB[ob + 8] = o1;
        }
        return;
    }
    {
        int row = (bx - PREP_CONV - PREP_TRAN) * 4 + (tid >> 6);   // 2052 rows
        int lane = tid & 63;
        float su = 0.f, sv = 0.f;
        if (row < HH * DD) {
            int h = row >> 9, d = row & 511;
            size_t wb = (size_t)h * DD * FF + (size_t)d * FF;
#pragma unroll
            for (int j = 0; j < 8; ++j) {
                int f = lane + 64 * j;
                float wv = W[wb + f];
                su += wv * u[(size_t)h * FF + f];
                sv += wv * v[(size_t)h * FF + f];
            }
        } else if (row < HH * DD + HH) {
            int h = row - HH * DD;
#pragma unroll
            for (int j = 0; j < 8; ++j) {
                int f = lane + 64 * j;
                float bvv = b[(size_t)h * FF + f];
                su += bvv * u[(size_t)h * FF + f];
                sv += bvv * v[(size_t)h * FF + f];
            }
        }
#pragma unroll
        for (int m = 1; m < 64; m <<= 1) {
            su += __shfl_xor(su, m, 64);
            sv += __shfl_xor(sv, m, 64);
        }
        if (lane == 0 && row < HH * DD + HH) {
            if (row < HH * DD) { g_tu[row] = su; g_tv[row] = sv; }
            else { g_bu[row - HH * DD] = su; g_bv[row - HH * DD] = sv; }
        }
    }
}

// ---------------- p[h][n] = nodes[n].t_u[h] + bu[h];  q likewise (vectorized loads) ----------------
__global__ __launch_bounds__(256) void k_pq() {
    int row = blockIdx.x * 4 + (threadIdx.x >> 6);    // 4096 blocks -> 16384 rows = H*N
    int lane = threadIdx.x & 63;
    int h = row >> 12, n = row & 4095;
    const f16* nb = g_catA + (size_t)n * KK + lane * 8;   // nodes slice, 8 contiguous d's per lane
    const float* tu = g_tu + h * DD + lane * 8;
    const float* tv = g_tv + h * DD + lane * 8;
    f16x8 nv8 = *(const f16x8*)nb;
    f32x4 tu0 = *(const f32x4*)tu, tu1 = *(const f32x4*)(tu + 4);
    f32x4 tv0 = *(const f32x4*)tv, tv1 = *(const f32x4*)(tv + 4);
    float pa = 0.f, qa = 0.f;
#pragma unroll
    for (int j = 0; j < 4; ++j) {
        float nv = (float)nv8[j];
        pa += nv * tu0[j];
        qa += nv * tv0[j];
    }
#pragma unroll
    for (int j = 0; j < 4; ++j) {
        float nv = (float)nv8[4 + j];
        pa += nv * tu1[j];
        qa += nv * tv1[j];
    }
#pragma unroll
    for (int m = 1; m < 64; m <<= 1) {
        pa += __shfl_xor(pa, m, 64);
        qa += __shfl_xor(qa, m, 64);
    }
    if (lane == 0) {
        g_p[row] = pa + g_bu[h];
        g_q[row] = qa + g_bv[h];
    }
}

// ---------------- concat GEMM: featsH[h][f][n] = f16(([nodes|X] @ [W_h;We])[n][f] + bcat)
//                  K=1024, BK=64, tile 128n x 128f, glds + XOR-swizzle ----------------
__global__ __launch_bounds__(256, 2) void k_gemm_feats() {
    __shared__ f16 As[128 * 64];        // 16 KB  [n][k], 128-B rows, chunks XOR-swizzled
    __shared__ f16 Bs[128 * 64];        // 16 KB  [f][k]
    int tid = threadIdx.x;
    int lane = tid & 63, wave = tid >> 6;        // 4 waves
    int wr = wave & 1, wf = wave >> 1;
    int c = lane & 15, g = lane >> 4;
    int n0 = blockIdx.x * 128, f0 = blockIdx.y * 128;
    int h = blockIdx.z;
    const f16* Bgl = g_catB + (size_t)h * FF * KK;
    int r8 = lane >> 3;                  // row within 8-row glds group
    int ksw = ((lane & 7) ^ r8) * 8;     // swizzled source k-chunk offset
    f32x4 acc[4][4] = {};
    for (int kk = 0; kk < KK; kk += 64) {
        __syncthreads();
#pragma unroll
        for (int j = 0; j < 4; ++j) {
            int row = wave * 32 + j * 8;
            glds16(g_catA + (size_t)(n0 + row + r8) * KK + kk + ksw, &As[row * 64]);
            glds16(Bgl    + (size_t)(f0 + row + r8) * KK + kk + ksw, &Bs[row * 64]);
        }
        __syncthreads();
#pragma unroll
        for (int s = 0; s < 2; ++s) {
            f16x8 af[4], bf[4];
#pragma unroll
            for (int i = 0; i < 4; ++i)
                af[i] = *(const f16x8*)&As[(wr * 64 + i * 16 + c) * 64 + (((s * 4 + g) ^ (c & 7)) * 8)];
#pragma unroll
            for (int jj = 0; jj < 4; ++jj)
                bf[jj] = *(const f16x8*)&Bs[(wf * 64 + jj * 16 + c) * 64 + (((s * 4 + g) ^ (c & 7)) * 8)];
#pragma unroll
            for (int i = 0; i < 4; ++i)
#pragma unroll
                for (int jj = 0; jj < 4; ++jj)
                    acc[i][jj] = __builtin_amdgcn_mfma_f32_16x16x32_f16(af[i], bf[jj], acc[i][jj], 0, 0, 0);
        }
    }
#pragma unroll
    for (int jj = 0; jj < 4; ++jj) {
        int f = f0 + wf * 64 + jj * 16 + c;
        float bv = g_bcat[h * FF + f];
#pragma unroll
        for (int i = 0; i < 4; ++i) {
            int r0 = n0 + wr * 64 + i * 16 + g * 4;
            f16x4 ov;
#pragma unroll
            for (int rr = 0; rr < 4; ++rr) ov[rr] = (f16)(acc[i][jj][rr] + bv);
            *(f16x4*)(g_featsH + ((size_t)h * FF + f) * NN + r0) = ov;
        }
    }
}

// ---------------- softmax stats: closed-form M (lrelu monotone), single Z pass ----------------
__global__ __launch_bounds__(256) void k_msz() {
    __shared__ float qsh[NN];
    __shared__ float red[256];
    int h = blockIdx.y;
    int tid = threadIdx.x;
    float lmax = -1e30f, lmin = 1e30f;
    for (int i = tid; i < NN; i += 256) {
        float qv = g_q[h * NN + i];
        qsh[i] = qv;
        lmax = fmaxf(lmax, qv);
        lmin = fminf(lmin, qv);
    }
    red[tid] = lmax;
    __syncthreads();
    for (int s = 128; s > 0; s >>= 1) {
        if (tid < s) red[tid] = fmaxf(red[tid], red[tid + s]);
        __syncthreads();
    }
    float qmax = red[0];
    __syncthreads();
    red[tid] = lmin;
    __syncthreads();
    for (int s = 128; s > 0; s >>= 1) {
        if (tid < s) red[tid] = fminf(red[tid], red[tid + s]);
        __syncthreads();
    }
    float qmin = red[0];
    __syncthreads();
    int nl = tid & 15, chunk = tid >> 4;             // 16 rows/block, 16 k-chunks of 256
    int n = blockIdx.x * 16 + nl;
    float pv = g_p[h * NN + n];
    float se = pv * (pv >= 0.f ? qmax : qmin);
    float M = fmaxf(se, 0.3f * se);
    float z = 0.f;
    int base = chunk * 256;
    for (int i = 0; i < 64; ++i) {
        f32x4 qv = *(const f32x4*)&qsh[base + i * 4];
#pragma unroll
        for (int k = 0; k < 4; ++k) {
            float s = pv * qv[k];
            s = fmaxf(s, 0.3f * s);
            z += __expf(s - M);
        }
    }
    red[chunk * 16 + nl] = z;
    __syncthreads();
    if (chunk == 0) {
        float Z = 0.f;
#pragma unroll
        for (int t = 0; t < 16; ++t) Z += red[t * 16 + nl];
        g_M[h * NN + n] = M;
        g_sc[h * NN + n] = 0.25f / Z;
    }
}

// ---------------- GEMM3 v10: identical tile/structure to R12 best, but 1-D grid 256 with
//                  grp = bx&7 (round-robin -> each XCD owns one (h,ks) group; featsH slice
//                  2MB becomes L2-resident, drain at L2 latency) ----------------
#define ALD 68   // A-tile padded row stride (f16)
__global__ __launch_bounds__(512, 2) void k_gemm_out() {
    __shared__ f16 As[128 * ALD];       // 17 KB  [n][k0..63]
    __shared__ f16 BsL[512 * 32];       // 32 KB  [f][k0..31]
    __shared__ f16 BsH[512 * 32];       // 32 KB  [f][k32..63]
    int bx = blockIdx.x;
    int grp = bx & 7;                            // XCD-resident (h,ks) group
    int h = grp >> 1, ks = grp & 1;
    int n0 = (bx >> 3) * 128;
    int tid = threadIdx.x;
    int lane = tid & 63, wave = tid >> 6;        // 8 waves
    int wr = wave & 1;                           // n half (0..1)
    int wf = wave >> 1;                          // f quarter (0..3)
    int c = lane & 15, g = lane >> 4;
    int wn = tid >> 2, kq = (tid & 3) * 16;      // weight-gen: row wn (0..127), 16 k's
    float pv = g_p[h * NN + n0 + wn];
    float mv = g_M[h * NN + n0 + wn];
    float sv = g_sc[h * NN + n0 + wn];
    const float* qh = g_q + h * NN + ks * 2048;
    const f16* Bgl = g_featsH + (size_t)h * FF * NN + (size_t)ks * 2048;
    int brow = lane >> 2;                        // glds: lane's row within a 16-row group
    int bksw = ((lane & 3) ^ (brow & 3)) * 8;    //       swizzled source k-chunk offset
    f32x4 acc[4][8] = {};
    for (int kk = 0; kk < 2048; kk += 64) {
        f16x8 w0, w1;
#pragma unroll
        for (int half = 0; half < 2; ++half) {
            f32x4 qa = *(const f32x4*)(qh + kk + kq + half * 8);
            f32x4 qb = *(const f32x4*)(qh + kk + kq + half * 8 + 4);
#pragma unroll
            for (int k = 0; k < 4; ++k) {
                float s = pv * qa[k];
                s = fmaxf(s, 0.3f * s);
                if (half == 0) w0[k] = (f16)(__expf(s - mv) * sv);
                else           w1[k] = (f16)(__expf(s - mv) * sv);
            }
#pragma unroll
            for (int k = 0; k < 4; ++k) {
                float s = pv * qb[k];
                s = fmaxf(s, 0.3f * s);
                if (half == 0) w0[4 + k] = (f16)(__expf(s - mv) * sv);
                else           w1[4 + k] = (f16)(__expf(s - mv) * sv);
            }
        }
        __syncthreads();   // previous interval's LDS readers done
        *(f16x8*)&As[wn * ALD + kq] = w0;
        *(f16x8*)&As[wn * ALD + kq + 8] = w1;
#pragma unroll
        for (int j = 0; j < 4; ++j) {
            int frow = wave * 64 + j * 16;
            glds16(Bgl + (size_t)(frow + brow) * NN + kk + bksw,      &BsL[frow * 32]);
            glds16(Bgl + (size_t)(frow + brow) * NN + kk + 32 + bksw, &BsH[frow * 32]);
        }
        __syncthreads();   // drain -> tiles ready
#pragma unroll
        for (int s = 0; s < 2; ++s) {
            const f16* Bsrc = (s == 0) ? BsL : BsH;
            f16x8 af[4], bfr[8];
#pragma unroll
            for (int i = 0; i < 4; ++i)
                af[i] = *(const f16x8*)&As[(wr * 64 + i * 16 + c) * ALD + s * 32 + g * 8];
#pragma unroll
            for (int jj = 0; jj < 8; ++jj)
                bfr[jj] = *(const f16x8*)&Bsrc[(wf * 128 + jj * 16 + c) * 32 + ((g ^ (c & 3)) * 8)];
#pragma unroll
            for (int i = 0; i < 4; ++i)
#pragma unroll
                for (int jj = 0; jj < 8; ++jj)
                    acc[i][jj] = __builtin_amdgcn_mfma_f32_16x16x32_f16(af[i], bfr[jj], acc[i][jj], 0, 0, 0);
        }
    }
    f16* O = g_oaccH + (size_t)grp * NN * FF;
#pragma unroll
    for (int jj = 0; jj < 8; ++jj) {
        int f = wf * 128 + jj * 16 + c;
#pragma unroll
        for (int i = 0; i < 4; ++i) {
            int r0 = n0 + wr * 64 + i * 16 + g * 4;
#pragma unroll
            for (int rr = 0; rr < 4; ++rr)
                O[(size_t)(r0 + rr) * FF + f] = (f16)acc[i][jj][rr];
        }
    }
}

// ---------------- final: out = relu(sum over 8 f16 slabs) (fp32 out) ----------------
__global__ void k_reduce(float* __restrict__ out) {
    size_t i = ((size_t)blockIdx.x * 256 + threadIdx.x) * 4;   // 2048 blocks
    const size_t NF = (size_t)NN * FF;
    f32x4 s = {0.f, 0.f, 0.f, 0.f};
#pragma unroll
    for (int sl = 0; sl < 8; ++sl) {
        f16x4 v = *(const f16x4*)(g_oaccH + sl * NF + i);
#pragma unroll
        for (int rr = 0; rr < 4; ++rr) s[rr] += (float)v[rr];
    }
    f32x4 o;
#pragma unroll
    for (int rr = 0; rr < 4; ++rr) o[rr] = fmaxf(s[rr], 0.f);
    *(f32x4*)(out + i) = o;
}

extern "C" void kernel_launch(void* const* d_in, const int* in_sizes, int n_in,
                              void* d_out, int out_size, void* d_ws, size_t ws_size,
                              hipStream_t stream) {
    (void)in_sizes; (void)n_in; (void)out_size; (void)d_ws; (void)ws_size;
    const float* nodes  = (const float*)d_in[0];
    const float* edges  = (const float*)d_in[1];
    const float* labels = (const float*)d_in[2];
    const float* We     = (const float*)d_in[3];
    const float* be     = (const float*)d_in[4];
    const float* W      = (const float*)d_in[5];
    const float* b      = (const float*)d_in[6];
    const float* u      = (const float*)d_in[7];
    const float* v      = (const float*)d_in[8];

    k_prep<<<PREP_CONV + PREP_TRAN + PREP_UV, 256, 0, stream>>>(nodes, edges, labels, We, W, be, b, u, v);
    k_pq<<<4096, 256, 0, stream>>>();
    k_gemm_feats<<<dim3(32, 4, 4), 256, 0, stream>>>();
    k_msz<<<dim3(256, 4), 256, 0, stream>>>();
    k_gemm_out<<<256, 512, 0, stream>>>();
    k_reduce<<<2048, 256, 0, stream>>>((float*)d_out);
}

// Round 15
// 247.727 us; speedup vs baseline: 1.0823x; 1.0823x over previous
//
#include <hip/hip_runtime.h>

#define NN 4096
#define DD 512
#define FF 512
#define HH 4
#define KK 1024   // concat GEMM depth

typedef _Float16 f16;
typedef f16 f16x8 __attribute__((ext_vector_type(8)));
typedef f16 f16x4 __attribute__((ext_vector_type(4)));
typedef float f32x4 __attribute__((ext_vector_type(4)));

// ---------------- async global->LDS (16 B per lane; LDS dest = uniform base + lane*16) ----------------
typedef __attribute__((address_space(1))) void gvoid;
typedef __attribute__((address_space(3))) void svoid;
__device__ __forceinline__ void glds16(const void* g, void* s) {
    __builtin_amdgcn_global_load_lds((gvoid*)g, (svoid*)s, 16, 0, 0);
}

// ---------------- static device workspace (fully rewritten every call) ----------------
__device__ __attribute__((aligned(16))) f16 g_catA[NN * KK];         //  8 MB  [n][ nodes(512) | X(512) ]
__device__ __attribute__((aligned(16))) f16 g_catB[HH * FF * KK];    //  4 MB  [h][f][ W_h^T(512) | We^T(512) ]
__device__ __attribute__((aligned(16))) f16 g_featsH[HH * FF * NN];  // 16 MB  (feats+e)^T
__device__ __attribute__((aligned(16))) f16 g_oaccH[(size_t)2 * HH * NN * FF]; // 33.5 MB f16 partial slabs
__device__ float g_Zp[2 * HH * NN];                                  // per-(h,ks) row weight-sums
__device__ float g_bcat[HH * FF];                                    // b_h[f] + be[f]
__device__ float g_tu[HH * DD], g_tv[HH * DD], g_bu[HH], g_bv[HH];
__device__ float g_p[HH * NN], g_q[HH * NN], g_M[HH * NN];

#define PREP_CONV 4104    // (2*NN*DD/4 + HH*FF) / 256 blocks
#define PREP_TRAN 320
#define PREP_UV   513

// ---------------- fused prep: fp32->f16 concat staging (vectorized) + transposes + u/v proj ----------------
__global__ __launch_bounds__(256) void k_prep(const float* __restrict__ nodes, const float* __restrict__ edges,
                                              const float* __restrict__ labels, const float* __restrict__ We,
                                              const float* __restrict__ W, const float* __restrict__ be,
                                              const float* __restrict__ b, const float* __restrict__ u,
                                              const float* __restrict__ v) {
    __shared__ float lds[64 * 65];
    int bx = blockIdx.x;
    int tid = threadIdx.x;
    if (bx < PREP_CONV) {
        int id = bx * 256 + tid;
        const int NQ = NN * DD / 4;              // 524288 float4 groups
        if (id < NQ) {                           // nodes -> catA[:, 0:512]
            f32x4 vv = *(const f32x4*)(nodes + (size_t)id * 4);
            f16x4 ov;
#pragma unroll
            for (int k = 0; k < 4; ++k) ov[k] = (f16)vv[k];
            *(f16x4*)&g_catA[(size_t)(id >> 7) * KK + (id & 127) * 4] = ov;
            return;
        }
        id -= NQ;
        if (id < NQ) {                           // edges+labels -> catA[:, 512:1024]
            f32x4 ev = *(const f32x4*)(edges  + (size_t)id * 4);
            f32x4 lv = *(const f32x4*)(labels + (size_t)id * 4);
            f16x4 ov;
#pragma unroll
            for (int k = 0; k < 4; ++k) ov[k] = (f16)(ev[k] + lv[k]);
            *(f16x4*)&g_catA[(size_t)(id >> 7) * KK + 512 + (id & 127) * 4] = ov;
            return;
        }
        id -= NQ;
        if (id < HH * FF) { g_bcat[id] = b[id] + be[id & 511]; return; }
        return;
    }
    if (bx < PREP_CONV + PREP_TRAN) {
        int bid = bx - PREP_CONV;                    // 0..319
        int mi = bid >> 6;                           // 0 = We, 1..4 = W head
        int t64 = bid & 63;
        const float* src = (mi == 0) ? We : (W + (size_t)(mi - 1) * DD * FF);
        int ti = t64 >> 3, tj = t64 & 7;             // 64x64 tile coords in [d][f]
        int r = tid >> 2, cseg = (tid & 3) * 16;
#pragma unroll
        for (int kq = 0; kq < 4; ++kq) {
            f32x4 vv = *(const f32x4*)(src + (size_t)(ti * 64 + r) * 512 + tj * 64 + cseg + kq * 4);
            *(f32x4*)&lds[r * 65 + cseg + kq * 4] = vv;
        }
        __syncthreads();
        int fl = tid >> 2, dseg = (tid & 3) * 16;
        f16x8 o0, o1;
#pragma unroll
        for (int k = 0; k < 8; ++k) o0[k] = (f16)lds[(dseg + k) * 65 + fl];
#pragma unroll
        for (int k = 0; k < 8; ++k) o1[k] = (f16)lds[(dseg + 8 + k) * 65 + fl];
        size_t frow = (size_t)(tj * 64 + fl);
        size_t dcol = (size_t)(ti * 64 + dseg);
        if (mi == 0) {                               // We^T -> every head's [512:1024] slice
#pragma unroll
            for (int hh = 0; hh < HH; ++hh) {
                size_t ob = ((size_t)hh * FF + frow) * KK + 512 + dcol;
                *(f16x8*)&g_catB[ob] = o0;
                *(f16x8*)&g_catB[ob + 8] = o1;
            }
        } else {                                     // W_h^T -> head's [0:512] slice
            size_t ob = ((size_t)(mi - 1) * FF + frow) * KK + dcol;
            *(f16x8*)&g_catB[ob] = o0;
            *(f16x8*)&g_catB[ob + 8] = o1;
        }
        return;
    }
    {
        int row = (bx - PREP_CONV - PREP_TRAN) * 4 + (tid >> 6);   // 2052 rows
        int lane = tid & 63;
        float su = 0.f, sv = 0.f;
        if (row < HH * DD) {
            int h = row >> 9, d = row & 511;
            size_t wb = (size_t)h * DD * FF + (size_t)d * FF;
#pragma unroll
            for (int j = 0; j < 8; ++j) {
                int f = lane + 64 * j;
                float wv = W[wb + f];
                su += wv * u[(size_t)h * FF + f];
                sv += wv * v[(size_t)h * FF + f];
            }
        } else if (row < HH * DD + HH) {
            int h = row - HH * DD;
#pragma unroll
            for (int j = 0; j < 8; ++j) {
                int f = lane + 64 * j;
                float bvv = b[(size_t)h * FF + f];
                su += bvv * u[(size_t)h * FF + f];
                sv += bvv * v[(size_t)h * FF + f];
            }
        }
#pragma unroll
        for (int m = 1; m < 64; m <<= 1) {
            su += __shfl_xor(su, m, 64);
            sv += __shfl_xor(sv, m, 64);
        }
        if (lane == 0 && row < HH * DD + HH) {
            if (row < HH * DD) { g_tu[row] = su; g_tv[row] = sv; }
            else { g_bu[row - HH * DD] = su; g_bv[row - HH * DD] = sv; }
        }
    }
}

// ---------------- p[h][n] = nodes[n].t_u[h] + bu[h];  q likewise (vectorized loads) ----------------
__global__ __launch_bounds__(256) void k_pq() {
    int row = blockIdx.x * 4 + (threadIdx.x >> 6);    // 4096 blocks -> 16384 rows = H*N
    int lane = threadIdx.x & 63;
    int h = row >> 12, n = row & 4095;
    const f16* nb = g_catA + (size_t)n * KK + lane * 8;   // nodes slice, 8 contiguous d's per lane
    const float* tu = g_tu + h * DD + lane * 8;
    const float* tv = g_tv + h * DD + lane * 8;
    f16x8 nv8 = *(const f16x8*)nb;
    f32x4 tu0 = *(const f32x4*)tu, tu1 = *(const f32x4*)(tu + 4);
    f32x4 tv0 = *(const f32x4*)tv, tv1 = *(const f32x4*)(tv + 4);
    float pa = 0.f, qa = 0.f;
#pragma unroll
    for (int j = 0; j < 4; ++j) {
        float nv = (float)nv8[j];
        pa += nv * tu0[j];
        qa += nv * tv0[j];
    }
#pragma unroll
    for (int j = 0; j < 4; ++j) {
        float nv = (float)nv8[4 + j];
        pa += nv * tu1[j];
        qa += nv * tv1[j];
    }
#pragma unroll
    for (int m = 1; m < 64; m <<= 1) {
        pa += __shfl_xor(pa, m, 64);
        qa += __shfl_xor(qa, m, 64);
    }
    if (lane == 0) {
        g_p[row] = pa + g_bu[h];
        g_q[row] = qa + g_bv[h];
    }
}

// ---------------- concat GEMM v3 (BK=128, 8 intervals): featsH[h][f][n] = f16(catA@catB^T + bcat)
//                  tile 128n x 128f, all-glds staging, 16-chunk XOR swizzle ----------------
__global__ __launch_bounds__(256, 2) void k_gemm_feats() {
    __shared__ f16 As[128 * 128];       // 32 KB  [n][k0..127], 256-B rows, chunk-swizzled
    __shared__ f16 Bs[128 * 128];       // 32 KB  [f][k0..127]
    int tid = threadIdx.x;
    int lane = tid & 63, wave = tid >> 6;        // 4 waves
    int wr = wave & 1, wc = wave >> 1;
    int c = lane & 15, g = lane >> 4;
    int n0 = blockIdx.x * 128, f0 = blockIdx.y * 128;
    int h = blockIdx.z;
    const f16* Bgl = g_catB + (size_t)h * FF * KK;
    int r4 = lane >> 4;                  // row within 4-row glds group (0..3)
    int ch = lane & 15;                  // chunk slot this lane fills (16 chunks of 16B per row)
    f32x4 acc[4][4] = {};
    for (int kk = 0; kk < KK; kk += 128) {
        __syncthreads();
#pragma unroll
        for (int j = 0; j < 8; ++j) {
            int rowb = wave * 32 + j * 4;        // wave stages rows [wave*32, wave*32+32)
            int row = rowb + r4;
            int src = (ch ^ (row & 15)) * 8;     // swizzled source k-chunk (f16 elems)
            glds16(g_catA + (size_t)(n0 + row) * KK + kk + src, &As[rowb * 128]);
            glds16(Bgl    + (size_t)(f0 + row) * KK + kk + src, &Bs[rowb * 128]);
        }
        __syncthreads();
#pragma unroll
        for (int s = 0; s < 4; ++s) {
            f16x8 af[4], bf[4];
#pragma unroll
            for (int i = 0; i < 4; ++i) {
                int ra = wr * 64 + i * 16 + c;
                af[i] = *(const f16x8*)&As[ra * 128 + (((s * 4 + g) ^ (ra & 15)) * 8)];
            }
#pragma unroll
            for (int jj = 0; jj < 4; ++jj) {
                int rb = wc * 64 + jj * 16 + c;
                bf[jj] = *(const f16x8*)&Bs[rb * 128 + (((s * 4 + g) ^ (rb & 15)) * 8)];
            }
#pragma unroll
            for (int i = 0; i < 4; ++i)
#pragma unroll
                for (int jj = 0; jj < 4; ++jj)
                    acc[i][jj] = __builtin_amdgcn_mfma_f32_16x16x32_f16(af[i], bf[jj], acc[i][jj], 0, 0, 0);
        }
    }
#pragma unroll
    for (int jj = 0; jj < 4; ++jj) {
        int f = f0 + wc * 64 + jj * 16 + c;
        float bv = g_bcat[h * FF + f];
#pragma unroll
        for (int i = 0; i < 4; ++i) {
            int r0 = n0 + wr * 64 + i * 16 + g * 4;
            f16x4 ov;
#pragma unroll
            for (int rr = 0; rr < 4; ++rr) ov[rr] = (f16)(acc[i][jj][rr] + bv);
            *(f16x4*)(g_featsH + ((size_t)h * FF + f) * NN + r0) = ov;
        }
    }
}

// ---------------- M only (closed form; Z now computed inside gemm_out) ----------------
__global__ __launch_bounds__(256) void k_mstat() {
    __shared__ float red[256];
    int h = blockIdx.x;
    int tid = threadIdx.x;
    float lmax = -1e30f, lmin = 1e30f;
    for (int i = tid; i < NN; i += 256) {
        float qv = g_q[h * NN + i];
        lmax = fmaxf(lmax, qv);
        lmin = fminf(lmin, qv);
    }
    red[tid] = lmax;
    __syncthreads();
    for (int s = 128; s > 0; s >>= 1) {
        if (tid < s) red[tid] = fmaxf(red[tid], red[tid + s]);
        __syncthreads();
    }
    float qmax = red[0];
    __syncthreads();
    red[tid] = lmin;
    __syncthreads();
    for (int s = 128; s > 0; s >>= 1) {
        if (tid < s) red[tid] = fminf(red[tid], red[tid + s]);
        __syncthreads();
    }
    float qmin = red[0];
#pragma unroll
    for (int j = 0; j < 16; ++j) {
        int n = tid + j * 256;
        float pv = g_p[h * NN + n];
        float se = pv * (pv >= 0.f ? qmax : qmin);
        g_M[h * NN + n] = fmaxf(se, 0.3f * se);
    }
}

// ---------------- GEMM3 (R12 structure + in-loop Z accumulation): unnormalized weights
//                  w = exp(s-M)/64 (scale cancels in reduce); Zp[grp][n] = row weight-sum ----------------
#define ALD 68   // A-tile padded row stride (f16)
__global__ __launch_bounds__(512, 2) void k_gemm_out() {
    __shared__ f16 As[128 * ALD];       // 17 KB  [n][k0..63]
    __shared__ f16 BsL[512 * 32];       // 32 KB  [f][k0..31]
    __shared__ f16 BsH[512 * 32];       // 32 KB  [f][k32..63]
    int tid = threadIdx.x;
    int lane = tid & 63, wave = tid >> 6;        // 8 waves
    int wr = wave & 1;                           // n half (0..1)
    int wf = wave >> 1;                          // f quarter (0..3)
    int c = lane & 15, g = lane >> 4;
    int n0 = blockIdx.x * 128;
    int h = blockIdx.y;
    int ks = blockIdx.z;                         // k-slice: m in [ks*2048, +2048)
    int wn = tid >> 2, kq = (tid & 3) * 16;      // weight-gen: row wn (0..127), 16 k's
    const float C = 0.015625f;                   // 1/64 overflow guard; cancels via Zp
    float pv = g_p[h * NN + n0 + wn];
    float mv = g_M[h * NN + n0 + wn];
    const float* qh = g_q + h * NN + ks * 2048;
    const f16* Bgl = g_featsH + (size_t)h * FF * NN + (size_t)ks * 2048;
    int brow = lane >> 2;                        // glds: lane's row within a 16-row group
    int bksw = ((lane & 3) ^ (brow & 3)) * 8;    //       swizzled source k-chunk offset
    float zacc = 0.f;
    f32x4 acc[4][8] = {};
    for (int kk = 0; kk < 2048; kk += 64) {
        f16x8 w0, w1;
#pragma unroll
        for (int half = 0; half < 2; ++half) {
            f32x4 qa = *(const f32x4*)(qh + kk + kq + half * 8);
            f32x4 qb = *(const f32x4*)(qh + kk + kq + half * 8 + 4);
#pragma unroll
            for (int k = 0; k < 4; ++k) {
                float s = pv * qa[k];
                s = fmaxf(s, 0.3f * s);
                float e = __expf(s - mv) * C;
                zacc += e;
                if (half == 0) w0[k] = (f16)e;
                else           w1[k] = (f16)e;
            }
#pragma unroll
            for (int k = 0; k < 4; ++k) {
                float s = pv * qb[k];
                s = fmaxf(s, 0.3f * s);
                float e = __expf(s - mv) * C;
                zacc += e;
                if (half == 0) w0[4 + k] = (f16)e;
                else           w1[4 + k] = (f16)e;
            }
        }
        __syncthreads();   // previous interval's LDS readers done
        *(f16x8*)&As[wn * ALD + kq] = w0;
        *(f16x8*)&As[wn * ALD + kq + 8] = w1;
#pragma unroll
        for (int j = 0; j < 4; ++j) {
            int frow = wave * 64 + j * 16;
            glds16(Bgl + (size_t)(frow + brow) * NN + kk + bksw,      &BsL[frow * 32]);
            glds16(Bgl + (size_t)(frow + brow) * NN + kk + 32 + bksw, &BsH[frow * 32]);
        }
        __syncthreads();   // drain -> tiles ready
#pragma unroll
        for (int s = 0; s < 2; ++s) {
            const f16* Bsrc = (s == 0) ? BsL : BsH;
            f16x8 af[4], bfr[8];
#pragma unroll
            for (int i = 0; i < 4; ++i)
                af[i] = *(const f16x8*)&As[(wr * 64 + i * 16 + c) * ALD + s * 32 + g * 8];
#pragma unroll
            for (int jj = 0; jj < 8; ++jj)
                bfr[jj] = *(const f16x8*)&Bsrc[(wf * 128 + jj * 16 + c) * 32 + ((g ^ (c & 3)) * 8)];
#pragma unroll
            for (int i = 0; i < 4; ++i)
#pragma unroll
                for (int jj = 0; jj < 8; ++jj)
                    acc[i][jj] = __builtin_amdgcn_mfma_f32_16x16x32_f16(af[i], bfr[jj], acc[i][jj], 0, 0, 0);
        }
    }
    // row weight-sum: 4 threads (kq quads) per row -> quad reduce, one writer
    zacc += __shfl_xor(zacc, 1, 64);
    zacc += __shfl_xor(zacc, 2, 64);
    if ((tid & 3) == 0) g_Zp[(size_t)(h * 2 + ks) * NN + n0 + wn] = zacc;
    f16* O = g_oaccH + (size_t)(h * 2 + ks) * NN * FF;
#pragma unroll
    for (int jj = 0; jj < 8; ++jj) {
        int f = wf * 128 + jj * 16 + c;
#pragma unroll
        for (int i = 0; i < 4; ++i) {
            int r0 = n0 + wr * 64 + i * 16 + g * 4;
#pragma unroll
            for (int rr = 0; rr < 4; ++rr)
                O[(size_t)(r0 + rr) * FF + f] = (f16)acc[i][jj][rr];
        }
    }
}

// ---------------- final: out = relu(sum_h (0.25/Z_h[n]) * (slab_h0 + slab_h1)) ----------------
__global__ void k_reduce(float* __restrict__ out) {
    int t = blockIdx.x * 256 + threadIdx.x;   // 2048 blocks; 4 f-elems per thread, one row n
    size_t i = (size_t)t * 4;
    int n = t >> 7;                           // i / 512
    const size_t NF = (size_t)NN * FF;
    f32x4 s = {0.f, 0.f, 0.f, 0.f};
#pragma unroll
    for (int h = 0; h < HH; ++h) {
        float Z = g_Zp[(size_t)(2 * h) * NN + n] + g_Zp[(size_t)(2 * h + 1) * NN + n];
        float sc = 0.25f / Z;
        f16x4 a = *(const f16x4*)(g_oaccH + (size_t)(2 * h) * NF + i);
        f16x4 bsl = *(const f16x4*)(g_oaccH + (size_t)(2 * h + 1) * NF + i);
#pragma unroll
        for (int rr = 0; rr < 4; ++rr) s[rr] += ((float)a[rr] + (float)bsl[rr]) * sc;
    }
    f32x4 o;
#pragma unroll
    for (int rr = 0; rr < 4; ++rr) o[rr] = fmaxf(s[rr], 0.f);
    *(f32x4*)(out + i) = o;
}

extern "C" void kernel_launch(void* const* d_in, const int* in_sizes, int n_in,
                              void* d_out, int out_size, void* d_ws, size_t ws_size,
                              hipStream_t stream) {
    (void)in_sizes; (void)n_in; (void)out_size; (void)d_ws; (void)ws_size;
    const float* nodes  = (const float*)d_in[0];
    const float* edges  = (const float*)d_in[1];
    const float* labels = (const float*)d_in[2];
    const float* We     = (const float*)d_in[3];
    const float* be     = (const float*)d_in[4];
    const float* W      = (const float*)d_in[5];
    const float* b      = (const float*)d_in[6];
    const float* u      = (const float*)d_in[7];
    const float* v      = (const float*)d_in[8];

    k_prep<<<PREP_CONV + PREP_TRAN + PREP_UV, 256, 0, stream>>>(nodes, edges, labels, We, W, be, b, u, v);
    k_pq<<<4096, 256, 0, stream>>>();
    k_gemm_feats<<<dim3(32, 4, 4), 256, 0, stream>>>();
    k_mstat<<<HH, 256, 0, stream>>>();
    k_gemm_out<<<dim3(32, 4, 2), 512, 0, stream>>>();
    k_reduce<<<2048, 256, 0, stream>>>((float*)d_out);
}